// Round 1
// 678.855 us; speedup vs baseline: 2.1004x; 2.1004x over previous
//
#include <hip/hip_runtime.h>
#include <cstdint>
#include <cstddef>

// ConvVFE: voxelize -> per-voxel mean -> MLP(10->32)+BN+ReLU -> voxel max
// -> concat -> MLP(64->128)+BN+ReLU -> voxel max ; plus voxel coords.
//
// R5: round-4 counters: kA_gstats 508us, MfmaUtil=0, VALUBusy=28%, 1.9e7 LDS
// bank conflicts -> layer-2 GEMM was scalar fp32 on the VALU (plus a twin
// apply pass and a 512MB y1 spill). This version puts layer 2 on the matrix
// cores:
//   - activations stored point-major bf16: XpL[Npad][32] (post-BN0 x0) and
//     XpU[Npad][32] (voxel max broadcast per point). MFMA A-frags become
//     single contiguous 16B loads per lane (wave reads 1KB contiguous).
//   - w1 split into bf16 hi+lo (two MFMA accumulations) for fp32-weight
//     accuracy.
//   - kA_mstats: MFMA GEMM accumulating sum(y), sum(y^2) for BN1.
//   - kB_mapply: MFMA GEMM + BN1 + ReLU staged in LDS (64x128 f32), then
//     voxel-driven gather-max: interior voxels plain coalesced stores,
//     only tile-straddling voxels use atomicMax. y1h / kC / chunk loop gone.

constexpr int M_IDS  = 220000;
constexpr int CH     = 256;
constexpr int NCHUNK = (M_IDS + CH - 1) / CH;   // 860

typedef __attribute__((ext_vector_type(8))) __bf16          bf16x8;
typedef __attribute__((ext_vector_type(8))) unsigned short  u16x8;
typedef __attribute__((ext_vector_type(4))) float           f32x4;

union U8 { u16x8 u; bf16x8 b; };

__device__ __forceinline__ uint16_t f2b(float f) {
    uint32_t u = __float_as_uint(f);
    u += 0x7fffu + ((u >> 16) & 1u);
    return (uint16_t)(u >> 16);
}
__device__ __forceinline__ float b2f(uint16_t h) {
    return __uint_as_float(((uint32_t)h) << 16);
}

__device__ __forceinline__ f32x4 mfma16(bf16x8 a, bf16x8 b, f32x4 c) {
    return __builtin_amdgcn_mfma_f32_16x16x32_bf16(a, b, c, 0, 0, 0);
}

// ---------------------------------------------------------------- k1: merge id + histogram
__global__ void k1_count(const float* __restrict__ pts, int* __restrict__ inv,
                         int* __restrict__ cnt, int N)
{
    int i = blockIdx.x * blockDim.x + threadIdx.x;
    if (i >= N) return;
    const float* p = pts + (size_t)i * 5;
    float b = p[0], x = p[1], y = p[2], z = p[3];
    float fx = floorf((x - 0.0f) / 0.32f);
    float fy = floorf((y + 40.0f) / 0.32f);
    float fz = floorf((z + 3.0f) / 4.0f);
    bool ok = (fx >= 0.0f) && (fx < 220.0f) && (fy >= 0.0f) && (fy < 250.0f) &&
              (fz >= 0.0f) && (fz < 1.0f);
    if (!ok) { inv[i] = -1; return; }
    int m = (int)b * 55000 + (int)fx * 250 + (int)fy + (int)fz;
    inv[i] = m;
    atomicAdd(&cnt[m], 1);
}

// ---------------------------------------------------------------- k2: two-level scans
__global__ void k2a_tot(const int* __restrict__ cnt, int* __restrict__ totO,
                        int* __restrict__ totC, int* __restrict__ np)
{
    __shared__ int so[CH], sc[CH];
    int t = threadIdx.x;
    int id = blockIdx.x * CH + t;
    int c = (id < M_IDS) ? cnt[id] : 0;
    so[t] = (c > 0) ? 1 : 0;
    sc[t] = c;
    __syncthreads();
    for (int s = CH / 2; s > 0; s >>= 1) {
        if (t < s) { so[t] += so[t + s]; sc[t] += sc[t + s]; }
        __syncthreads();
    }
    if (t == 0) { totO[blockIdx.x] = so[0]; totC[blockIdx.x] = sc[0]; atomicAdd(np, sc[0]); }
}

__global__ void k2b_scan(const int* __restrict__ totO, const int* __restrict__ totC,
                         int* __restrict__ baseO, int* __restrict__ baseC)
{
    __shared__ int a[1024], bb[1024];
    int t = threadIdx.x;
    int vo = (t < NCHUNK) ? totO[t] : 0;
    int vc = (t < NCHUNK) ? totC[t] : 0;
    a[t] = vo; bb[t] = vc;
    __syncthreads();
    for (int off = 1; off < 1024; off <<= 1) {
        int xa = (t >= off) ? a[t - off] : 0;
        int xb = (t >= off) ? bb[t - off] : 0;
        __syncthreads();
        a[t] += xa; bb[t] += xb;
        __syncthreads();
    }
    baseO[t] = a[t] - vo;   // exclusive
    baseC[t] = bb[t] - vc;
}

__global__ void k2c_index(const int* __restrict__ cnt, const int* __restrict__ baseO,
                          const int* __restrict__ baseC, int* __restrict__ idxArr,
                          int* __restrict__ bOff, int* __restrict__ vOff,
                          int* __restrict__ vCnt, float* __restrict__ outCoords)
{
    __shared__ int a[CH], bb[CH];
    int t = threadIdx.x;
    int id = blockIdx.x * CH + t;
    int c = (id < M_IDS) ? cnt[id] : 0;
    int occ = (c > 0) ? 1 : 0;
    a[t] = occ; bb[t] = c;
    __syncthreads();
    for (int off = 1; off < CH; off <<= 1) {
        int xa = (t >= off) ? a[t - off] : 0;
        int xb = (t >= off) ? bb[t - off] : 0;
        __syncthreads();
        a[t] += xa; bb[t] += xb;
        __syncthreads();
    }
    if (id >= M_IDS) return;
    int g  = baseO[blockIdx.x] + a[t] - occ;
    int bo = baseC[blockIdx.x] + bb[t] - c;
    idxArr[id] = g;
    bOff[id]   = bo;
    if (occ) {
        vOff[g] = bo;
        vCnt[g] = c;
        int b2 = id / 55000;
        int rm = id % 55000;
        int cx = rm / 250;
        int cy = rm % 250;
        outCoords[(size_t)g * 4 + 0] = (float)b2;
        outCoords[(size_t)g * 4 + 1] = 0.0f;
        outCoords[(size_t)g * 4 + 2] = (float)cy;
        outCoords[(size_t)g * 4 + 3] = (float)cx;
    }
}

// ---------------------------------------------------------------- k3: scatter points to sorted order
__global__ void k3_order(const int* __restrict__ inv, const int* __restrict__ bOff,
                         const int* __restrict__ idxArr, int* __restrict__ cursor,
                         int* __restrict__ ord, int* __restrict__ vS, int N)
{
    int i = blockIdx.x * blockDim.x + threadIdx.x;
    if (i >= N) return;
    int m = inv[i];
    if (m < 0) return;
    int slot = atomicAdd(&cursor[m], 1);
    int j = bOff[m] + slot;
    ord[j] = i;
    vS[j]  = idxArr[m];
}

// ---------------------------------------------------------------- k4: per-voxel xyz mean (gather)
__global__ void k4_mean(const float* __restrict__ pts, const int* __restrict__ ord,
                        const int* __restrict__ vOff, const int* __restrict__ vCnt,
                        float* __restrict__ meanArr, int V)
{
    int g = blockIdx.x * blockDim.x + threadIdx.x;
    if (g >= V) return;
    int off = vOff[g], c = vCnt[g];
    float sx = 0.0f, sy = 0.0f, sz = 0.0f;
    for (int p = 0; p < c; p++) {
        const float* q = pts + (size_t)ord[off + p] * 5;
        sx += q[1]; sy += q[2]; sz += q[3];
    }
    float fc = (float)c;
    meanArr[(size_t)g * 3 + 0] = sx / fc;
    meanArr[(size_t)g * 3 + 1] = sy / fc;
    meanArr[(size_t)g * 3 + 2] = sz / fc;
}

// ---------------------------------------------------------------- k5: y0 = feats @ w0, point-major bf16
__global__ __launch_bounds__(256)
void k5_y0(const float* __restrict__ pts, const float* __restrict__ w0,
           const int* __restrict__ ord, const int* __restrict__ vS,
           const float* __restrict__ meanArr, uint16_t* __restrict__ XpL)
{
    int j = blockIdx.x * 256 + threadIdx.x;   // grid = Npad/256 exactly
    float y0[32];
#pragma unroll
    for (int c = 0; c < 32; c++) y0[c] = 0.0f;
    int v = vS[j];
    if (v >= 0) {
        int i = ord[j];
        const float* p = pts + (size_t)i * 5;
        float x = p[1], y = p[2], z = p[3], it = p[4];
        float fx = floorf((x - 0.0f) / 0.32f);
        float fy = floorf((y + 40.0f) / 0.32f);
        float f[10];
        f[0] = x; f[1] = y; f[2] = z; f[3] = it;
        f[4] = x - meanArr[(size_t)v * 3 + 0];
        f[5] = y - meanArr[(size_t)v * 3 + 1];
        f[6] = z - meanArr[(size_t)v * 3 + 2];
        f[7] = x - (fx * 0.32f + 0.16f);
        f[8] = y - (fy * 0.32f - 39.84f);
        f[9] = z + 1.0f;
#pragma unroll
        for (int d = 0; d < 10; d++) {
            float fd = f[d];
#pragma unroll
            for (int c = 0; c < 32; c++) y0[c] += fd * w0[d * 32 + c];
        }
    }
    uint32_t pk[16];
#pragma unroll
    for (int k = 0; k < 16; k++)
        pk[k] = (uint32_t)f2b(y0[2 * k]) | ((uint32_t)f2b(y0[2 * k + 1]) << 16);
    uint4* rp = (uint4*)(XpL + (size_t)j * 32);
#pragma unroll
    for (int k = 0; k < 4; k++)
        rp[k] = make_uint4(pk[4 * k], pk[4 * k + 1], pk[4 * k + 2], pk[4 * k + 3]);
}

// ---------------------------------------------------------------- k6: BN0 stats (point-major)
__global__ __launch_bounds__(256)
void k6_stats0(const uint16_t* __restrict__ XpL, float* __restrict__ stats0, int Npad)
{
    __shared__ float sl[64];
    int t = threadIdx.x;
    if (t < 64) sl[t] = 0.0f;
    __syncthreads();
    float s[32], q[32];
#pragma unroll
    for (int c = 0; c < 32; c++) { s[c] = 0.0f; q[c] = 0.0f; }
    for (int j = blockIdx.x * 256 + t; j < Npad; j += gridDim.x * 256) {
        const uint4* rp = (const uint4*)(XpL + (size_t)j * 32);
#pragma unroll
        for (int k = 0; k < 4; k++) {
            uint4 u = rp[k];
            uint32_t uu[4] = {u.x, u.y, u.z, u.w};
#pragma unroll
            for (int e = 0; e < 4; e++) {
                float f0 = __uint_as_float(uu[e] << 16);
                float f1 = __uint_as_float(uu[e] & 0xffff0000u);
                int c = k * 8 + e * 2;
                s[c]     += f0; q[c]     += f0 * f0;
                s[c + 1] += f1; q[c + 1] += f1 * f1;
            }
        }
    }
    int lane = t & 63;
#pragma unroll
    for (int cc = 0; cc < 32; cc++) {     // staggered start: spread banks/addresses
        int c = (cc + lane) & 31;
        atomicAdd(&sl[c],      s[c]);
        atomicAdd(&sl[32 + c], q[c]);
    }
    __syncthreads();
    if (t < 32) {
        atomicAdd(&stats0[t],      sl[t]);
        atomicAdd(&stats0[32 + t], sl[32 + t]);
    }
}

// ---------------------------------------------------------------- BN finalize
__global__ void k_bnfin(const float* __restrict__ stats, const int* __restrict__ np,
                        const float* __restrict__ g, const float* __restrict__ b,
                        float* __restrict__ sb, int C)
{
    int c = blockIdx.x * blockDim.x + threadIdx.x;
    if (c >= C) return;
    float n   = (float)(*np);
    float mu  = stats[c] / n;
    float var = stats[C + c] / n - mu * mu;
    float s   = g[c] / sqrtf(var + 1e-3f);
    sb[c]     = s;
    sb[C + c] = b[c] - mu * s;
}

// ---------------------------------------------------------------- k7: x0 = relu(bn0(y0)) in place; zero invalid rows
__global__ __launch_bounds__(256)
void k7_apply0(uint16_t* __restrict__ XpL, uint16_t* __restrict__ XpU,
               const int* __restrict__ vS, const float* __restrict__ sb0)
{
    __shared__ float s0[64];
    int t = threadIdx.x;
    if (t < 64) s0[t] = sb0[t];
    __syncthreads();
    int j = blockIdx.x * 256 + t;                 // grid = Npad/256 exactly
    uint4* rpL = (uint4*)(XpL + (size_t)j * 32);
    int v = vS[j];
    if (v < 0) {
        uint4 z = make_uint4(0u, 0u, 0u, 0u);
        uint4* rpU = (uint4*)(XpU + (size_t)j * 32);
#pragma unroll
        for (int k = 0; k < 4; k++) { rpL[k] = z; rpU[k] = z; }
        return;
    }
#pragma unroll
    for (int k = 0; k < 4; k++) {
        uint4 u = rpL[k];
        uint32_t uu[4] = {u.x, u.y, u.z, u.w};
        uint32_t w[4];
#pragma unroll
        for (int e = 0; e < 4; e++) {
            int c = k * 8 + e * 2;
            float f0 = __uint_as_float(uu[e] << 16);
            float f1 = __uint_as_float(uu[e] & 0xffff0000u);
            float e0 = fmaxf(f0 * s0[c]     + s0[32 + c],     0.0f);
            float e1 = fmaxf(f1 * s0[c + 1] + s0[32 + c + 1], 0.0f);
            w[e] = (uint32_t)f2b(e0) | ((uint32_t)f2b(e1) << 16);
        }
        rpL[k] = make_uint4(w[0], w[1], w[2], w[3]);
    }
}

// ---------------------------------------------------------------- k8: voxel max of x0, broadcast into XpU rows
__global__ __launch_bounds__(256)
void k8_xmax(const uint16_t* __restrict__ XpL, uint16_t* __restrict__ XpU,
             const int* __restrict__ vOff, const int* __restrict__ vCnt, int V)
{
    int t = threadIdx.x;
    int g = blockIdx.x * 4 + (t >> 6);
    if (g >= V) return;
    int lane = t & 63;
    int c = lane & 31, h = lane >> 5;
    int off = vOff[g], n = vCnt[g];
    float m = 0.0f;                      // relu >= 0
    for (int i = h; i < n; i += 2)
        m = fmaxf(m, b2f(XpL[(size_t)(off + i) * 32 + c]));
    m = fmaxf(m, __shfl_xor(m, 32));
    uint16_t mb = f2b(m);                // exact: max of bf16 values
    for (int i = h; i < n; i += 2)
        XpU[(size_t)(off + i) * 32 + c] = mb;
}

// ---------------------------------------------------------------- W frags: bf16 hi/lo split of w1
__device__ __forceinline__ void load_wsplit(const float* __restrict__ w1, int cb,
                                            int l15, int lg, bf16x8* Bhi, bf16x8* Blo)
{
    int col = cb + l15;
    int kr  = lg * 8;
#pragma unroll
    for (int nb = 0; nb < 4; nb++) {
#pragma unroll
        for (int ks = 0; ks < 2; ks++) {
            U8 h, l;
#pragma unroll
            for (int jj = 0; jj < 8; jj++) {
                float w = w1[(ks * 32 + kr + jj) * 128 + col + nb * 16];
                uint16_t hb = f2b(w);
                h.u[jj] = hb;
                l.u[jj] = f2b(w - b2f(hb));
            }
            Bhi[nb * 2 + ks] = h.b;
            Blo[nb * 2 + ks] = l.b;
        }
    }
}

// ---------------------------------------------------------------- kA: MFMA GEMM stats pass (BN1)
__global__ __launch_bounds__(256)
void kA_mstats(const uint16_t* __restrict__ XpL, const uint16_t* __restrict__ XpU,
               const float* __restrict__ w1, const int* __restrict__ np,
               float* __restrict__ stats1, int ntiles)
{
    int t = threadIdx.x;
    int wv = t >> 6, lane = t & 63;
    int l15 = lane & 15, lg = lane >> 4;
    int rowSel = wv & 1;                 // which 32-row half of the 64-pt tile
    int cb     = (wv >> 1) * 64;         // which 64-col half of the 128 outputs

    bf16x8 Bhi[8], Blo[8];
    load_wsplit(w1, cb, l15, lg, Bhi, Blo);

    int nv = *np;
    float s[4], q[4];
#pragma unroll
    for (int nb = 0; nb < 4; nb++) { s[nb] = 0.0f; q[nb] = 0.0f; }

    for (int tile = blockIdx.x; tile < ntiles; tile += gridDim.x) {
        int tb = tile * 64;
        if (tb >= nv) break;             // zero tail rows contribute 0
        int rbase = tb + rowSel * 32;
        f32x4 acc[2][4];
#pragma unroll
        for (int m = 0; m < 2; m++)
#pragma unroll
            for (int nb = 0; nb < 4; nb++)
                acc[m][nb] = (f32x4){0.0f, 0.0f, 0.0f, 0.0f};
#pragma unroll
        for (int m = 0; m < 2; m++) {
            size_t r = (size_t)(rbase + m * 16 + l15);
            U8 tL, tU;
            tL.u = *(const u16x8*)(XpL + r * 32 + lg * 8);
            tU.u = *(const u16x8*)(XpU + r * 32 + lg * 8);
#pragma unroll
            for (int nb = 0; nb < 4; nb++) {
                acc[m][nb] = mfma16(tL.b, Bhi[nb * 2],     acc[m][nb]);
                acc[m][nb] = mfma16(tL.b, Blo[nb * 2],     acc[m][nb]);
                acc[m][nb] = mfma16(tU.b, Bhi[nb * 2 + 1], acc[m][nb]);
                acc[m][nb] = mfma16(tU.b, Blo[nb * 2 + 1], acc[m][nb]);
            }
        }
#pragma unroll
        for (int m = 0; m < 2; m++)
#pragma unroll
            for (int nb = 0; nb < 4; nb++)
#pragma unroll
                for (int r = 0; r < 4; r++) {
                    float y = acc[m][nb][r];
                    s[nb] += y; q[nb] += y * y;
                }
    }
#pragma unroll
    for (int nb = 0; nb < 4; nb++) {
        s[nb] += __shfl_xor(s[nb], 16);
        s[nb] += __shfl_xor(s[nb], 32);
        q[nb] += __shfl_xor(q[nb], 16);
        q[nb] += __shfl_xor(q[nb], 32);
    }
    if (lane < 16) {
#pragma unroll
        for (int nb = 0; nb < 4; nb++) {
            atomicAdd(&stats1[cb + nb * 16 + lane],       s[nb]);
            atomicAdd(&stats1[128 + cb + nb * 16 + lane], q[nb]);
        }
    }
}

// ---------------------------------------------------------------- kB: MFMA GEMM + BN1 + ReLU + fused voxel max
__global__ __launch_bounds__(256)
void kB_mapply(const uint16_t* __restrict__ XpL, const uint16_t* __restrict__ XpU,
               const float* __restrict__ w1, const int* __restrict__ vS,
               const int* __restrict__ vOff, const int* __restrict__ vCnt,
               const int* __restrict__ np, const float* __restrict__ sb1,
               unsigned int* __restrict__ out, int ntiles)
{
    __shared__ float els[64 * 128];      // 32 KiB: relu(bn(y)) for one 64-pt tile
    int t = threadIdx.x;
    int wv = t >> 6, lane = t & 63;
    int l15 = lane & 15, lg = lane >> 4;
    int rowSel = wv & 1;
    int cb     = (wv >> 1) * 64;

    bf16x8 Bhi[8], Blo[8];
    load_wsplit(w1, cb, l15, lg, Bhi, Blo);

    float sc[4], bc[4];
#pragma unroll
    for (int nb = 0; nb < 4; nb++) {
        int c = cb + nb * 16 + l15;
        sc[nb] = sb1[c];
        bc[nb] = sb1[128 + c];
    }

    int nv = *np;
    int cg = t & 127;                    // gather channel
    int slot = t >> 7;                   // gather voxel slot (0/1)

    for (int tile = blockIdx.x; tile < ntiles; tile += gridDim.x) {
        int tb = tile * 64;
        if (tb >= nv) break;             // no valid rows, no outputs
        int rbase = tb + rowSel * 32;
        f32x4 acc[2][4];
#pragma unroll
        for (int m = 0; m < 2; m++)
#pragma unroll
            for (int nb = 0; nb < 4; nb++)
                acc[m][nb] = (f32x4){0.0f, 0.0f, 0.0f, 0.0f};
#pragma unroll
        for (int m = 0; m < 2; m++) {
            size_t r = (size_t)(rbase + m * 16 + l15);
            U8 tL, tU;
            tL.u = *(const u16x8*)(XpL + r * 32 + lg * 8);
            tU.u = *(const u16x8*)(XpU + r * 32 + lg * 8);
#pragma unroll
            for (int nb = 0; nb < 4; nb++) {
                acc[m][nb] = mfma16(tL.b, Bhi[nb * 2],     acc[m][nb]);
                acc[m][nb] = mfma16(tL.b, Blo[nb * 2],     acc[m][nb]);
                acc[m][nb] = mfma16(tU.b, Bhi[nb * 2 + 1], acc[m][nb]);
                acc[m][nb] = mfma16(tU.b, Blo[nb * 2 + 1], acc[m][nb]);
            }
        }
        __syncthreads();                 // protect previous tile's gather readers
#pragma unroll
        for (int m = 0; m < 2; m++) {
            int rloc = rowSel * 32 + m * 16 + lg * 4;
#pragma unroll
            for (int nb = 0; nb < 4; nb++) {
                int c = cb + nb * 16 + l15;
#pragma unroll
                for (int r = 0; r < 4; r++) {
                    float e = fmaxf(acc[m][nb][r] * sc[nb] + bc[nb], 0.0f);
                    els[(rloc + r) * 128 + c] = e;
                }
            }
        }
        __syncthreads();
        // voxel-driven gather-max over this tile's rows (points sorted by voxel)
        int lastRow = nv - 1 - tb; if (lastRow > 63) lastRow = 63;
        int gFirst = vS[tb];
        int gLast  = vS[tb + lastRow];
        for (int g = gFirst + slot; g <= gLast; g += 2) {
            int off = vOff[g], end = off + vCnt[g];
            int a  = off > tb ? off : tb;
            int e2 = end < tb + 64 ? end : tb + 64;
            float mx = 0.0f;
            for (int p2 = a; p2 < e2; p2++)
                mx = fmaxf(mx, els[(p2 - tb) * 128 + cg]);
            size_t oa = (size_t)g * 128 + cg;
            if (off >= tb && end <= tb + 64) out[oa] = __float_as_uint(mx); // interior: single writer
            else if (mx > 0.0f) atomicMax(&out[oa], __float_as_uint(mx));   // tile-straddling voxel
        }
    }
}

// ---------------------------------------------------------------- launch
extern "C" void kernel_launch(void* const* d_in, const int* in_sizes, int n_in,
                              void* d_out, int out_size, void* d_ws, size_t ws_size,
                              hipStream_t stream)
{
    const float* pts = (const float*)d_in[0];
    const float* w0  = (const float*)d_in[1];
    const float* g0  = (const float*)d_in[2];
    const float* b0  = (const float*)d_in[3];
    const float* w1  = (const float*)d_in[4];
    const float* g1  = (const float*)d_in[5];
    const float* b1  = (const float*)d_in[6];

    int N      = in_sizes[0] / 5;
    int V      = out_size / 132;
    int Npad   = (N + 255) & ~255;
    int ntiles = Npad / 64;

    char* ws = (char*)d_ws;
    size_t off = 0;
    auto alloc = [&](size_t bytes) { size_t r = off; off = (off + bytes + 255) & ~(size_t)255; return r; };

    int*   inv     = (int*)(ws + alloc((size_t)N * 4));
    int*   ord     = (int*)(ws + alloc((size_t)Npad * 4));
    int*   vS      = (int*)(ws + alloc((size_t)Npad * 4));
    size_t zOff    = off;                                   // zero block start
    int*   cnt     = (int*)(ws + alloc((size_t)M_IDS * 4));
    int*   cursor  = (int*)(ws + alloc((size_t)M_IDS * 4));
    float* stats   = (float*)(ws + alloc(320 * 4));         // bn0: 64 | bn1: 256
    int*   np      = (int*)(ws + alloc(4));
    size_t zBytes  = off - zOff;
    int*   bOff    = (int*)(ws + alloc((size_t)M_IDS * 4));
    int*   idxArr  = (int*)(ws + alloc((size_t)M_IDS * 4));
    int*   vOff    = (int*)(ws + alloc((size_t)M_IDS * 4));
    int*   vCnt    = (int*)(ws + alloc((size_t)M_IDS * 4));
    int*   totO    = (int*)(ws + alloc(1024 * 4));
    int*   totC    = (int*)(ws + alloc(1024 * 4));
    int*   baseO   = (int*)(ws + alloc(1024 * 4));
    int*   baseC   = (int*)(ws + alloc(1024 * 4));
    float* sb0     = (float*)(ws + alloc(64 * 4));
    float* sb1     = (float*)(ws + alloc(256 * 4));
    float* meanArr = (float*)(ws + alloc((size_t)V * 12));
    uint16_t* XpL  = (uint16_t*)(ws + alloc((size_t)Npad * 32 * 2));
    uint16_t* XpU  = (uint16_t*)(ws + alloc((size_t)Npad * 32 * 2));
    (void)ws_size;

    hipMemsetAsync(ws + zOff, 0, zBytes, stream);
    hipMemsetAsync(vS, 0xFF, (size_t)Npad * 4, stream);
    hipMemsetAsync(d_out, 0, (size_t)V * 128 * 4, stream);

    int blocksN = (N + 255) / 256;
    float* outF = (float*)d_out;

    k1_count<<<blocksN, 256, 0, stream>>>(pts, inv, cnt, N);
    k2a_tot<<<NCHUNK, CH, 0, stream>>>(cnt, totO, totC, np);
    k2b_scan<<<1, 1024, 0, stream>>>(totO, totC, baseO, baseC);
    k2c_index<<<NCHUNK, CH, 0, stream>>>(cnt, baseO, baseC, idxArr, bOff, vOff, vCnt,
                                         outF + (size_t)V * 128);
    k3_order<<<blocksN, 256, 0, stream>>>(inv, bOff, idxArr, cursor, ord, vS, N);
    k4_mean<<<(V + 255) / 256, 256, 0, stream>>>(pts, ord, vOff, vCnt, meanArr, V);
    k5_y0<<<Npad / 256, 256, 0, stream>>>(pts, w0, ord, vS, meanArr, XpL);
    k6_stats0<<<512, 256, 0, stream>>>(XpL, stats, Npad);
    k_bnfin<<<1, 32, 0, stream>>>(stats, np, g0, b0, sb0, 32);
    k7_apply0<<<Npad / 256, 256, 0, stream>>>(XpL, XpU, vS, sb0);
    k8_xmax<<<(V + 3) / 4, 256, 0, stream>>>(XpL, XpU, vOff, vCnt, V);
    kA_mstats<<<1024, 256, 0, stream>>>(XpL, XpU, w1, np, stats + 64, ntiles);
    k_bnfin<<<1, 128, 0, stream>>>(stats + 64, np, g1, b1, sb1, 128);
    kB_mapply<<<2048, 256, 0, stream>>>(XpL, XpU, w1, vS, vOff, vCnt, np, sb1,
                                        (unsigned int*)d_out, ntiles);
}

// Round 2
// 598.435 us; speedup vs baseline: 2.3826x; 1.1344x over previous
//
#include <hip/hip_runtime.h>
#include <cstdint>
#include <cstddef>

// ConvVFE: voxelize -> per-voxel mean -> MLP(10->32)+BN+ReLU -> voxel max
// -> concat -> MLP(64->128)+BN+ReLU -> voxel max ; plus voxel coords.
//
// R6: round-5 counters: kB_mapply 162us (MfmaUtil 8% -> only ~13us is MFMA;
// VALU 50%, 4e6 LDS conflicts); kA_mstats is a full duplicate GEMM; k4/k5
// random-gather via ord; k6/k7 are extra full passes over X.
// This version:
//  - monotone-BN trick: sign(s)=sign(g1), so voxel max of relu(bn(y)) =
//    relu(bn(max y)) for s>=0 / relu(bn(min y)) for s<0. kB gathers max/min
//    of RAW y (sign-selected), accumulates BN1 stats in the same pass, and
//    a tiny k_final applies bn+relu per voxel. kA_mstats DELETED.
//  - k3 scatters the 16B point payload (pts4) so k4/k5 read sorted
//    contiguous data; ord[] gone.
//  - BN0 stats fused into k5 (register butterfly); k6 gone.
//  - BN0 apply fused into k8's voxel-max pass; k7 gone.
//  - els stride 128->132 f32: staging is 2-way banked (free), conflicts ~0.

constexpr int M_IDS  = 220000;
constexpr int CH     = 256;
constexpr int NCHUNK = (M_IDS + CH - 1) / CH;   // 860
constexpr int NB1    = 1024;                    // kB grid / stats partials
constexpr int ELS    = 132;                     // els row stride (f32)

typedef __attribute__((ext_vector_type(8))) __bf16          bf16x8;
typedef __attribute__((ext_vector_type(8))) unsigned short  u16x8;
typedef __attribute__((ext_vector_type(4))) float           f32x4;

union U8 { u16x8 u; bf16x8 b; };

__device__ __forceinline__ uint16_t f2b(float f) {
    uint32_t u = __float_as_uint(f);
    u += 0x7fffu + ((u >> 16) & 1u);
    return (uint16_t)(u >> 16);
}
__device__ __forceinline__ float b2f(uint16_t h) {
    return __uint_as_float(((uint32_t)h) << 16);
}

__device__ __forceinline__ f32x4 mfma16(bf16x8 a, bf16x8 b, f32x4 c) {
    return __builtin_amdgcn_mfma_f32_16x16x32_bf16(a, b, c, 0, 0, 0);
}

// ---------------------------------------------------------------- k1: merge id + histogram
__global__ void k1_count(const float* __restrict__ pts, int* __restrict__ inv,
                         int* __restrict__ cnt, int N)
{
    int i = blockIdx.x * blockDim.x + threadIdx.x;
    if (i >= N) return;
    const float* p = pts + (size_t)i * 5;
    float b = p[0], x = p[1], y = p[2], z = p[3];
    float fx = floorf((x - 0.0f) / 0.32f);
    float fy = floorf((y + 40.0f) / 0.32f);
    float fz = floorf((z + 3.0f) / 4.0f);
    bool ok = (fx >= 0.0f) && (fx < 220.0f) && (fy >= 0.0f) && (fy < 250.0f) &&
              (fz >= 0.0f) && (fz < 1.0f);
    if (!ok) { inv[i] = -1; return; }
    int m = (int)b * 55000 + (int)fx * 250 + (int)fy + (int)fz;
    inv[i] = m;
    atomicAdd(&cnt[m], 1);
}

// ---------------------------------------------------------------- k2: two-level scans
__global__ void k2a_tot(const int* __restrict__ cnt, int* __restrict__ totO,
                        int* __restrict__ totC, int* __restrict__ np)
{
    __shared__ int so[CH], sc[CH];
    int t = threadIdx.x;
    int id = blockIdx.x * CH + t;
    int c = (id < M_IDS) ? cnt[id] : 0;
    so[t] = (c > 0) ? 1 : 0;
    sc[t] = c;
    __syncthreads();
    for (int s = CH / 2; s > 0; s >>= 1) {
        if (t < s) { so[t] += so[t + s]; sc[t] += sc[t + s]; }
        __syncthreads();
    }
    if (t == 0) { totO[blockIdx.x] = so[0]; totC[blockIdx.x] = sc[0]; atomicAdd(np, sc[0]); }
}

__global__ void k2b_scan(const int* __restrict__ totO, const int* __restrict__ totC,
                         int* __restrict__ baseO, int* __restrict__ baseC)
{
    __shared__ int a[1024], bb[1024];
    int t = threadIdx.x;
    int vo = (t < NCHUNK) ? totO[t] : 0;
    int vc = (t < NCHUNK) ? totC[t] : 0;
    a[t] = vo; bb[t] = vc;
    __syncthreads();
    for (int off = 1; off < 1024; off <<= 1) {
        int xa = (t >= off) ? a[t - off] : 0;
        int xb = (t >= off) ? bb[t - off] : 0;
        __syncthreads();
        a[t] += xa; bb[t] += xb;
        __syncthreads();
    }
    baseO[t] = a[t] - vo;   // exclusive
    baseC[t] = bb[t] - vc;
}

__global__ void k2c_index(const int* __restrict__ cnt, const int* __restrict__ baseO,
                          const int* __restrict__ baseC, int* __restrict__ idxArr,
                          int* __restrict__ bOff, int* __restrict__ vOff,
                          int* __restrict__ vCnt, float* __restrict__ outCoords)
{
    __shared__ int a[CH], bb[CH];
    int t = threadIdx.x;
    int id = blockIdx.x * CH + t;
    int c = (id < M_IDS) ? cnt[id] : 0;
    int occ = (c > 0) ? 1 : 0;
    a[t] = occ; bb[t] = c;
    __syncthreads();
    for (int off = 1; off < CH; off <<= 1) {
        int xa = (t >= off) ? a[t - off] : 0;
        int xb = (t >= off) ? bb[t - off] : 0;
        __syncthreads();
        a[t] += xa; bb[t] += xb;
        __syncthreads();
    }
    if (id >= M_IDS) return;
    int g  = baseO[blockIdx.x] + a[t] - occ;
    int bo = baseC[blockIdx.x] + bb[t] - c;
    idxArr[id] = g;
    bOff[id]   = bo;
    if (occ) {
        vOff[g] = bo;
        vCnt[g] = c;
        int b2 = id / 55000;
        int rm = id % 55000;
        int cx = rm / 250;
        int cy = rm % 250;
        outCoords[(size_t)g * 4 + 0] = (float)b2;
        outCoords[(size_t)g * 4 + 1] = 0.0f;
        outCoords[(size_t)g * 4 + 2] = (float)cy;
        outCoords[(size_t)g * 4 + 3] = (float)cx;
    }
}

// ---------------------------------------------------------------- k3: scatter point payload to sorted order
__global__ void k3_order(const float* __restrict__ pts, const int* __restrict__ inv,
                         const int* __restrict__ bOff, const int* __restrict__ idxArr,
                         int* __restrict__ cursor, float4* __restrict__ pts4,
                         int* __restrict__ vS, int N)
{
    int i = blockIdx.x * blockDim.x + threadIdx.x;
    if (i >= N) return;
    int m = inv[i];
    if (m < 0) return;
    const float* p = pts + (size_t)i * 5;
    float x = p[1], y = p[2], z = p[3], it = p[4];
    int slot = atomicAdd(&cursor[m], 1);
    int j = bOff[m] + slot;
    pts4[j] = make_float4(x, y, z, it);
    vS[j]   = idxArr[m];
}

// ---------------------------------------------------------------- k4: per-voxel xyz mean (contiguous gather)
__global__ void k4_mean(const float4* __restrict__ pts4, const int* __restrict__ vOff,
                        const int* __restrict__ vCnt, float* __restrict__ meanArr, int V)
{
    int g = blockIdx.x * blockDim.x + threadIdx.x;
    if (g >= V) return;
    int off = vOff[g], c = vCnt[g];
    float sx = 0.0f, sy = 0.0f, sz = 0.0f;
    for (int p = 0; p < c; p++) {
        float4 q = pts4[off + p];
        sx += q.x; sy += q.y; sz += q.z;
    }
    float fc = (float)c;
    meanArr[(size_t)g * 3 + 0] = sx / fc;
    meanArr[(size_t)g * 3 + 1] = sy / fc;
    meanArr[(size_t)g * 3 + 2] = sz / fc;
}

// ---------------------------------------------------------------- k5: y0 = feats @ w0 (point-major bf16) + fused BN0 stats
__global__ __launch_bounds__(256)
void k5_y0(const float4* __restrict__ pts4, const float* __restrict__ w0,
           const int* __restrict__ vS, const float* __restrict__ meanArr,
           uint16_t* __restrict__ XpL, float* __restrict__ stats0, int Npad)
{
    __shared__ float sl[64];
    int t = threadIdx.x;
    if (t < 64) sl[t] = 0.0f;
    __syncthreads();
    float s[32], q[32];
#pragma unroll
    for (int c = 0; c < 32; c++) { s[c] = 0.0f; q[c] = 0.0f; }

    for (int j = blockIdx.x * 256 + t; j < Npad; j += gridDim.x * 256) {
        float y0[32];
#pragma unroll
        for (int c = 0; c < 32; c++) y0[c] = 0.0f;
        int v = vS[j];
        if (v >= 0) {
            float4 P = pts4[j];
            float x = P.x, y = P.y, z = P.z, it = P.w;
            float fx = floorf((x - 0.0f) / 0.32f);
            float fy = floorf((y + 40.0f) / 0.32f);
            float f[10];
            f[0] = x; f[1] = y; f[2] = z; f[3] = it;
            f[4] = x - meanArr[(size_t)v * 3 + 0];
            f[5] = y - meanArr[(size_t)v * 3 + 1];
            f[6] = z - meanArr[(size_t)v * 3 + 2];
            f[7] = x - (fx * 0.32f + 0.16f);
            f[8] = y - (fy * 0.32f - 39.84f);
            f[9] = z + 1.0f;
#pragma unroll
            for (int d = 0; d < 10; d++) {
                float fd = f[d];
#pragma unroll
                for (int c = 0; c < 32; c++) y0[c] += fd * w0[d * 32 + c];
            }
        }
        uint32_t pk[16];
#pragma unroll
        for (int k = 0; k < 16; k++)
            pk[k] = (uint32_t)f2b(y0[2 * k]) | ((uint32_t)f2b(y0[2 * k + 1]) << 16);
        uint4* rp = (uint4*)(XpL + (size_t)j * 32);
#pragma unroll
        for (int k = 0; k < 4; k++)
            rp[k] = make_uint4(pk[4 * k], pk[4 * k + 1], pk[4 * k + 2], pk[4 * k + 3]);
#pragma unroll
        for (int c = 0; c < 32; c++) { s[c] += y0[c]; q[c] += y0[c] * y0[c]; }
    }

    // per-wave butterfly (static indices), one lane per channel adds to LDS
    int lane = t & 63;
#pragma unroll
    for (int c = 0; c < 32; c++) {
#pragma unroll
        for (int m = 1; m < 64; m <<= 1) {
            s[c] += __shfl_xor(s[c], m);
            q[c] += __shfl_xor(q[c], m);
        }
        if (lane == c) {
            atomicAdd(&sl[c],      s[c]);
            atomicAdd(&sl[32 + c], q[c]);
        }
    }
    __syncthreads();
    if (t < 64) atomicAdd(&stats0[t], sl[t]);
}

// ---------------------------------------------------------------- BN finalize
__global__ void k_bnfin(const float* __restrict__ stats, const int* __restrict__ np,
                        const float* __restrict__ g, const float* __restrict__ b,
                        float* __restrict__ sb, int C)
{
    int c = blockIdx.x * blockDim.x + threadIdx.x;
    if (c >= C) return;
    float n   = (float)(*np);
    float mu  = stats[c] / n;
    float var = stats[C + c] / n - mu * mu;
    float s   = g[c] / sqrtf(var + 1e-3f);
    sb[c]     = s;
    sb[C + c] = b[c] - mu * s;
}

// ---------------------------------------------------------------- k8: BN0 apply + voxel max, broadcast into XpU
__global__ __launch_bounds__(256)
void k8_xmax(uint16_t* __restrict__ XpL, uint16_t* __restrict__ XpU,
             const int* __restrict__ vOff, const int* __restrict__ vCnt,
             const float* __restrict__ sb0, int V)
{
    int t = threadIdx.x;
    int g = blockIdx.x * 4 + (t >> 6);
    if (g >= V) return;
    int lane = t & 63;
    int c = lane & 31, h = lane >> 5;
    float sc = sb0[c], bc = sb0[32 + c];
    int off = vOff[g], n = vCnt[g];
    float m = 0.0f;                      // relu >= 0
    for (int i = h; i < n; i += 2) {
        size_t a = (size_t)(off + i) * 32 + c;
        float e = fmaxf(b2f(XpL[a]) * sc + bc, 0.0f);
        XpL[a] = f2b(e);
        m = fmaxf(m, e);                 // f2b monotone: f2b(max e) == max f2b(e)
    }
    m = fmaxf(m, __shfl_xor(m, 32));
    uint16_t mb = f2b(m);
    for (int i = h; i < n; i += 2)
        XpU[(size_t)(off + i) * 32 + c] = mb;
}

// ---------------------------------------------------------------- W frags: bf16 hi/lo split of w1
__device__ __forceinline__ void load_wsplit(const float* __restrict__ w1, int cb,
                                            int l15, int lg, bf16x8* Bhi, bf16x8* Blo)
{
    int col = cb + l15;
    int kr  = lg * 8;
#pragma unroll
    for (int nb = 0; nb < 4; nb++) {
#pragma unroll
        for (int ks = 0; ks < 2; ks++) {
            U8 h, l;
#pragma unroll
            for (int jj = 0; jj < 8; jj++) {
                float w = w1[(ks * 32 + kr + jj) * 128 + col + nb * 16];
                uint16_t hb = f2b(w);
                h.u[jj] = hb;
                l.u[jj] = f2b(w - b2f(hb));
            }
            Bhi[nb * 2 + ks] = h.b;
            Blo[nb * 2 + ks] = l.b;
        }
    }
}

// ---------------------------------------------------------------- kB: MFMA GEMM + sign-aware voxel max/min of RAW y + BN1 stats
__global__ __launch_bounds__(256)
void kB_mapply(const uint16_t* __restrict__ XpL, const uint16_t* __restrict__ XpU,
               const float* __restrict__ w1, const float* __restrict__ g1,
               const int* __restrict__ vS, const int* __restrict__ vOff,
               const int* __restrict__ vCnt, const int* __restrict__ np,
               unsigned int* __restrict__ out, float* __restrict__ sPart, int ntiles)
{
    __shared__ float els[64 * ELS];      // raw y for one 64-pt tile (2-way banked)
    int t = threadIdx.x;
    int wv = t >> 6, lane = t & 63;
    int l15 = lane & 15, lg = lane >> 4;
    int rowSel = wv & 1;
    int cb     = (wv >> 1) * 64;

    bf16x8 Bhi[8], Blo[8];
    load_wsplit(w1, cb, l15, lg, Bhi, Blo);

    int nv = *np;
    int cg = t & 127;                    // gather channel
    int slot = t >> 7;                   // gather voxel slot (0/1)
    uint32_t sgnm = (g1[cg] < 0.0f) ? 0x80000000u : 0u;   // flip => max gathers min
    float ssum = 0.0f, qsum = 0.0f;

    for (int tile = blockIdx.x; tile < ntiles; tile += gridDim.x) {
        int tb = tile * 64;
        if (tb >= nv) break;             // uniform across block
        int rbase = tb + rowSel * 32;
        f32x4 acc[2][4];
#pragma unroll
        for (int m = 0; m < 2; m++)
#pragma unroll
            for (int nb = 0; nb < 4; nb++)
                acc[m][nb] = (f32x4){0.0f, 0.0f, 0.0f, 0.0f};
#pragma unroll
        for (int m = 0; m < 2; m++) {
            size_t r = (size_t)(rbase + m * 16 + l15);
            U8 tL, tU;
            tL.u = *(const u16x8*)(XpL + r * 32 + lg * 8);
            tU.u = *(const u16x8*)(XpU + r * 32 + lg * 8);
#pragma unroll
            for (int nb = 0; nb < 4; nb++) {
                acc[m][nb] = mfma16(tL.b, Bhi[nb * 2],     acc[m][nb]);
                acc[m][nb] = mfma16(tL.b, Blo[nb * 2],     acc[m][nb]);
                acc[m][nb] = mfma16(tU.b, Bhi[nb * 2 + 1], acc[m][nb]);
                acc[m][nb] = mfma16(tU.b, Blo[nb * 2 + 1], acc[m][nb]);
            }
        }
        __syncthreads();                 // protect previous tile's gather readers
#pragma unroll
        for (int m = 0; m < 2; m++) {
            int rloc = rowSel * 32 + m * 16 + lg * 4;
#pragma unroll
            for (int nb = 0; nb < 4; nb++) {
                int c = cb + nb * 16 + l15;
#pragma unroll
                for (int r = 0; r < 4; r++)
                    els[(rloc + r) * ELS + c] = acc[m][nb][r];   // RAW y
            }
        }
        __syncthreads();
        // voxel-driven gather over this tile's rows (points sorted by voxel)
        int lastRow = nv - 1 - tb; if (lastRow > 63) lastRow = 63;
        int gFirst = vS[tb];
        int gLast  = vS[tb + lastRow];
        for (int g = gFirst + slot; g <= gLast; g += 2) {
            int off = vOff[g], end = off + vCnt[g];
            int a  = off > tb ? off : tb;
            int e2 = end < tb + 64 ? end : tb + 64;
            float mx = __uint_as_float(0xff800000u);   // -inf (flipped domain)
            for (int p2 = a; p2 < e2; p2++) {
                float v = els[(p2 - tb) * ELS + cg];
                ssum += v; qsum += v * v;
                mx = fmaxf(mx, __uint_as_float(__float_as_uint(v) ^ sgnm));
            }
            uint32_t u = __float_as_uint(mx);
            uint32_t enc = (u & 0x80000000u) ? ~u : (u | 0x80000000u);  // order-preserving
            size_t oa = (size_t)g * 128 + cg;
            if (off >= tb && end <= tb + 64) out[oa] = enc;             // interior
            else atomicMax(&out[oa], enc);                              // straddler
        }
    }
    // BN1 stat partials: combine t / t+128, plain store per block
    __syncthreads();
    els[t] = ssum; els[256 + t] = qsum;
    __syncthreads();
    if (t < 128) {
        sPart[(size_t)cg * NB1 + blockIdx.x]         = els[t] + els[t + 128];
        sPart[(size_t)(128 + cg) * NB1 + blockIdx.x] = els[256 + t] + els[256 + t + 128];
    }
}

// ---------------------------------------------------------------- reduce stat partials
__global__ void k_red1(const float* __restrict__ part, float* __restrict__ stats1)
{
    __shared__ float red[4];
    int o = blockIdx.x, t = threadIdx.x;
    float s = 0.0f;
    for (int k = t; k < NB1; k += 256) s += part[(size_t)o * NB1 + k];
#pragma unroll
    for (int m = 1; m < 64; m <<= 1) s += __shfl_xor(s, m);
    if ((t & 63) == 0) red[t >> 6] = s;
    __syncthreads();
    if (t == 0) stats1[o] = red[0] + red[1] + red[2] + red[3];
}

// ---------------------------------------------------------------- k_final: decode + BN1 + ReLU over out
__global__ void k_final(unsigned int* __restrict__ out, const float* __restrict__ sb1,
                        const float* __restrict__ g1, int n4)
{
    int i = blockIdx.x * 256 + threadIdx.x;
    if (i >= n4) return;
    uint4 e = ((const uint4*)out)[i];
    int c0 = (i & 31) * 4;
    uint32_t ee[4] = {e.x, e.y, e.z, e.w};
    float r[4];
#pragma unroll
    for (int j = 0; j < 4; j++) {
        int c = c0 + j;
        uint32_t u = (ee[j] & 0x80000000u) ? (ee[j] ^ 0x80000000u) : ~ee[j];
        float f = __uint_as_float(u);
        uint32_t sg = (g1[c] < 0.0f) ? 0x80000000u : 0u;
        f = __uint_as_float(__float_as_uint(f) ^ sg);   // unflip for s<0 channels
        r[j] = fmaxf(f * sb1[c] + sb1[128 + c], 0.0f);
    }
    ((float4*)out)[i] = make_float4(r[0], r[1], r[2], r[3]);
}

// ---------------------------------------------------------------- launch
extern "C" void kernel_launch(void* const* d_in, const int* in_sizes, int n_in,
                              void* d_out, int out_size, void* d_ws, size_t ws_size,
                              hipStream_t stream)
{
    const float* pts = (const float*)d_in[0];
    const float* w0  = (const float*)d_in[1];
    const float* g0  = (const float*)d_in[2];
    const float* b0  = (const float*)d_in[3];
    const float* w1  = (const float*)d_in[4];
    const float* g1  = (const float*)d_in[5];
    const float* b1  = (const float*)d_in[6];

    int N      = in_sizes[0] / 5;
    int V      = out_size / 132;
    int Npad   = (N + 255) & ~255;
    int ntiles = Npad / 64;

    char* ws = (char*)d_ws;
    size_t off = 0;
    auto alloc = [&](size_t bytes) { size_t r = off; off = (off + bytes + 255) & ~(size_t)255; return r; };

    int*    inv     = (int*)(ws + alloc((size_t)N * 4));
    float4* pts4    = (float4*)(ws + alloc((size_t)Npad * 16));
    int*    vS      = (int*)(ws + alloc((size_t)Npad * 4));
    size_t  zOff    = off;                                   // zero block start
    int*    cnt     = (int*)(ws + alloc((size_t)M_IDS * 4));
    int*    cursor  = (int*)(ws + alloc((size_t)M_IDS * 4));
    float*  stats   = (float*)(ws + alloc(320 * 4));         // bn0: 64 | bn1: 256
    int*    np      = (int*)(ws + alloc(4));
    size_t  zBytes  = off - zOff;
    int*    bOff    = (int*)(ws + alloc((size_t)M_IDS * 4));
    int*    idxArr  = (int*)(ws + alloc((size_t)M_IDS * 4));
    int*    vOff    = (int*)(ws + alloc((size_t)M_IDS * 4));
    int*    vCnt    = (int*)(ws + alloc((size_t)M_IDS * 4));
    int*    totO    = (int*)(ws + alloc(1024 * 4));
    int*    totC    = (int*)(ws + alloc(1024 * 4));
    int*    baseO   = (int*)(ws + alloc(1024 * 4));
    int*    baseC   = (int*)(ws + alloc(1024 * 4));
    float*  sb0     = (float*)(ws + alloc(64 * 4));
    float*  sb1     = (float*)(ws + alloc(256 * 4));
    float*  sPart   = (float*)(ws + alloc((size_t)256 * NB1 * 4));
    float*  meanArr = (float*)(ws + alloc((size_t)V * 12));
    uint16_t* XpL   = (uint16_t*)(ws + alloc((size_t)Npad * 32 * 2));
    uint16_t* XpU   = (uint16_t*)(ws + alloc((size_t)Npad * 32 * 2));
    (void)ws_size;

    hipMemsetAsync(ws + zOff, 0, zBytes, stream);
    hipMemsetAsync(vS, 0xFF, (size_t)Npad * 4, stream);
    hipMemsetAsync(d_out, 0, (size_t)V * 128 * 4, stream);

    int blocksN = (N + 255) / 256;
    float* outF = (float*)d_out;

    k1_count<<<blocksN, 256, 0, stream>>>(pts, inv, cnt, N);
    k2a_tot<<<NCHUNK, CH, 0, stream>>>(cnt, totO, totC, np);
    k2b_scan<<<1, 1024, 0, stream>>>(totO, totC, baseO, baseC);
    k2c_index<<<NCHUNK, CH, 0, stream>>>(cnt, baseO, baseC, idxArr, bOff, vOff, vCnt,
                                         outF + (size_t)V * 128);
    k3_order<<<blocksN, 256, 0, stream>>>(pts, inv, bOff, idxArr, cursor, pts4, vS, N);
    k4_mean<<<(V + 255) / 256, 256, 0, stream>>>(pts4, vOff, vCnt, meanArr, V);
    k5_y0<<<512, 256, 0, stream>>>(pts4, w0, vS, meanArr, XpL, stats, Npad);
    k_bnfin<<<1, 32, 0, stream>>>(stats, np, g0, b0, sb0, 32);
    k8_xmax<<<(V + 3) / 4, 256, 0, stream>>>(XpL, XpU, vOff, vCnt, sb0, V);
    kB_mapply<<<NB1, 256, 0, stream>>>(XpL, XpU, w1, g1, vS, vOff, vCnt, np,
                                       (unsigned int*)d_out, sPart, ntiles);
    k_red1<<<256, 256, 0, stream>>>(sPart, stats + 64);
    k_bnfin<<<1, 128, 0, stream>>>(stats + 64, np, g1, b1, sb1, 128);
    k_final<<<(V * 32 + 255) / 256, 256, 0, stream>>>((unsigned int*)d_out, sb1, g1, V * 32);
}